// Round 7
// baseline (212.587 us; speedup 1.0000x reference)
//
#include <hip/hip_runtime.h>
#include <hip/hip_bf16.h>

// b=1, c=256, h=w=64 -> n=4096 pixels, 4 heads, hd=64, 32 groups x 8 ch.
// scale = hd^-0.5 = 0.125, folded into Wq (K0) and bq (K1 epilogue).
#define NPIX 4096
#define CCH  256
#define HD   64
#define GSIZE 32768   // 8 ch * 4096 pix per group

typedef __bf16 bf16x8 __attribute__((ext_vector_type(8)));
typedef __bf16 bf16x4 __attribute__((ext_vector_type(4)));
typedef float  f32x4  __attribute__((ext_vector_type(4)));

#define PPITCH 72    // attn P-tile pitch (bf16)
#define CPITCH 68    // attn combine pitch (f32)
#define XPITCH 264   // X/F panel pitch (bf16)

// MFMA 16x16x32_bf16 layouts (verified m89/m91; used R2-R6):
//   A[m=lane&15][k=quad*8+j]; B[k=quad*8+j][n=lane&15]; C: row=quad*4+reg, col=lane&15

// ---------------------------------------------------------------------------
// K0: blocks 0..255: per-(group,1/8th) partial sums -> psum/pssq[256].
//     blocks 256..319: weight fp32->bf16 convert (Wq scaled 0.125).
// ---------------------------------------------------------------------------
__global__ __launch_bounds__(256) void stats_wconv(
    const float* __restrict__ X,
    const float* __restrict__ Wq, const float* __restrict__ Wk,
    const float* __restrict__ Wv, const float* __restrict__ Wp,
    float* __restrict__ psum, float* __restrict__ pssq, __bf16* __restrict__ Wb)
{
    const int bid = blockIdx.x, t = threadIdx.x;
    if (bid < 256) {
        const float* base = X + bid * 4096;   // (g = bid>>3, seg = bid&7)
        float sum = 0.f, ssq = 0.f;
        #pragma unroll
        for (int k = 0; k < 4; ++k) {
            float4 v = *(const float4*)(base + t * 4 + k * 1024);
            sum += v.x + v.y + v.z + v.w;
            ssq += v.x * v.x + v.y * v.y + v.z * v.z + v.w * v.w;
        }
        #pragma unroll
        for (int off = 1; off < 64; off <<= 1) {
            sum += __shfl_xor(sum, off);
            ssq += __shfl_xor(ssq, off);
        }
        __shared__ float red[2][4];
        const int wv = t >> 6;
        if ((t & 63) == 0) { red[0][wv] = sum; red[1][wv] = ssq; }
        __syncthreads();
        if (t == 0) {
            psum[bid] = red[0][0] + red[0][1] + red[0][2] + red[0][3];
            pssq[bid] = red[1][0] + red[1][1] + red[1][2] + red[1][3];
        }
    } else {
        const int j0 = (bid - 256) * 4096 + t * 16;
        const int m  = j0 >> 16;
        const float* W = (m == 0) ? Wq : (m == 1) ? Wk : (m == 2) ? Wv : Wp;
        const float sc = (m == 0) ? 0.125f : 1.f;
        const int off = j0 & 65535;
        #pragma unroll
        for (int k = 0; k < 4; ++k) {
            float4 v = *(const float4*)(W + off + k * 4);
            bf16x4 o;
            o[0] = (__bf16)(v.x * sc); o[1] = (__bf16)(v.y * sc);
            o[2] = (__bf16)(v.z * sc); o[3] = (__bf16)(v.w * sc);
            *(bf16x4*)(Wb + m * 65536 + off + k * 4) = o;
        }
    }
}

// ---------------------------------------------------------------------------
// K1: fused GroupNorm-apply + QKV MFMA GEMM. grid (64 pixblk, 6: z*2+och).
// Prologue folds the 8 stats partials/group into per-channel affine (LDS).
// Stage affine-applied bf16 X panel [64 pix][256 c]; each wave: 16 pix x 128 oc.
// ---------------------------------------------------------------------------
__global__ __launch_bounds__(256) void gn_qkv(
    const float* __restrict__ X, const float* __restrict__ gamma,
    const float* __restrict__ beta,
    const float* __restrict__ psum, const float* __restrict__ pssq,
    const __bf16* __restrict__ Wb,
    const float* __restrict__ bq, const float* __restrict__ bk,
    const float* __restrict__ bv,
    __bf16* __restrict__ Qb, __bf16* __restrict__ Kb, __bf16* __restrict__ Vb)
{
    __shared__ __bf16 tile[64 * XPITCH];
    __shared__ float al[256], bl[256];

    const int t = threadIdx.x, lane = t & 63, wave = t >> 6;
    const int l16 = lane & 15, quad = lane >> 4;
    const int p0 = blockIdx.x * 64;
    const int z = blockIdx.y >> 1, och = blockIdx.y & 1;

    // per-channel affine coeffs from partials (channel = t)
    {
        const int g = t >> 3;
        float s = 0.f, q = 0.f;
        #pragma unroll
        for (int j = 0; j < 8; ++j) { s += psum[g * 8 + j]; q += pssq[g * 8 + j]; }
        const float mu  = s * (1.f / GSIZE);
        const float var = q * (1.f / GSIZE) - mu * mu;
        const float a = gamma[t] * rsqrtf(var + 1e-6f);
        al[t] = a;
        bl[t] = beta[t] - mu * a;
    }
    __syncthreads();

    // stage: wave w handles channels [w*64, w*64+64), lane = pix
    #pragma unroll 4
    for (int i = 0; i < 16; ++i) {
        const int c4 = wave * 64 + i * 4;
        f32x4 a4 = *(const f32x4*)(al + c4);
        f32x4 b4 = *(const f32x4*)(bl + c4);
        bf16x4 pk;
        pk[0] = (__bf16)(X[(c4 + 0) * NPIX + p0 + lane] * a4[0] + b4[0]);
        pk[1] = (__bf16)(X[(c4 + 1) * NPIX + p0 + lane] * a4[1] + b4[1]);
        pk[2] = (__bf16)(X[(c4 + 2) * NPIX + p0 + lane] * a4[2] + b4[2]);
        pk[3] = (__bf16)(X[(c4 + 3) * NPIX + p0 + lane] * a4[3] + b4[3]);
        *(bf16x4*)(tile + lane * XPITCH + c4) = pk;
    }
    __syncthreads();

    const int pw = wave * 16;
    bf16x8 xf[8];
    #pragma unroll
    for (int kc = 0; kc < 8; ++kc)
        xf[kc] = *(const bf16x8*)(tile + (pw + l16) * XPITCH + kc * 32 + quad * 8);

    const __bf16* Wz = Wb + z * 65536;
    const float* bias = (z == 0) ? bq : (z == 1) ? bk : bv;

    if (z < 2) {
        const float qs = (z == 0) ? 0.125f : 1.f;
        __bf16* dst = (z == 0) ? Qb : Kb;
        #pragma unroll
        for (int grp = 0; grp < 2; ++grp) {
            f32x4 acc[4] = {};
            #pragma unroll
            for (int kc = 0; kc < 8; ++kc) {
                #pragma unroll
                for (int u = 0; u < 4; ++u) {
                    bf16x8 wf = *(const bf16x8*)(Wz + (och * 128 + (grp * 4 + u) * 16 + l16) * CCH + kc * 32 + quad * 8);
                    acc[u] = __builtin_amdgcn_mfma_f32_16x16x32_bf16(wf, xf[kc], acc[u], 0, 0, 0);
                }
            }
            #pragma unroll
            for (int u = 0; u < 4; ++u) {
                const int ot = och * 8 + grp * 4 + u;       // 0..15
                f32x4 bz = *(const f32x4*)(bias + och * 128 + (grp * 4 + u) * 16 + quad * 4);
                bf16x4 o;
                o[0] = (__bf16)(acc[u][0] + bz[0] * qs);
                o[1] = (__bf16)(acc[u][1] + bz[1] * qs);
                o[2] = (__bf16)(acc[u][2] + bz[2] * qs);
                o[3] = (__bf16)(acc[u][3] + bz[3] * qs);
                const int head = ot >> 2, dloc = (ot & 3) * 16 + quad * 4;
                *(bf16x4*)(dst + head * (NPIX * HD) + (p0 + pw + l16) * HD + dloc) = o;
            }
        }
    } else {
        #pragma unroll
        for (int grp = 0; grp < 2; ++grp) {
            f32x4 acc[4] = {};
            #pragma unroll
            for (int kc = 0; kc < 8; ++kc) {
                #pragma unroll
                for (int u = 0; u < 4; ++u) {
                    bf16x8 wf = *(const bf16x8*)(Wz + (och * 128 + (grp * 4 + u) * 16 + l16) * CCH + kc * 32 + quad * 8);
                    acc[u] = __builtin_amdgcn_mfma_f32_16x16x32_bf16(xf[kc], wf, acc[u], 0, 0, 0);
                }
            }
            #pragma unroll
            for (int u = 0; u < 4; ++u) {
                const int oc = och * 128 + (grp * 4 + u) * 16 + l16;
                const float bz = bias[oc];
                bf16x4 o;
                o[0] = (__bf16)(acc[u][0] + bz); o[1] = (__bf16)(acc[u][1] + bz);
                o[2] = (__bf16)(acc[u][2] + bz); o[3] = (__bf16)(acc[u][3] + bz);
                *(bf16x4*)(Vb + oc * NPIX + p0 + pw + quad * 4) = o;
            }
        }
    }
}

// ---------------------------------------------------------------------------
// K2: bf16 MFMA attention, max-free softmax, S^T orientation, 8-way key split.
// grid 1024: (head, qtile32, half). Block = 4 waves; wave w owns keys
// [half*2048 + w*512, +512) in 8 iters of 64. No barriers in main loop.
// l via fp32 psum + post-loop quad shuffle (off the matrix pipe).
// LDS: P-tile unioned with combine buffer (barrier separates lifetimes).
// Writes fp32 partial O (flat pix*256+c~ layout) + partial l per half.
// ---------------------------------------------------------------------------
__global__ __launch_bounds__(256, 4) void attn_mfma(
    const __bf16* __restrict__ Qb, const __bf16* __restrict__ Kb,
    const __bf16* __restrict__ Vb, float* __restrict__ Pb, float* __restrict__ Lb)
{
    __shared__ __align__(16) char smem[35840];
    __bf16* pt = (__bf16*)smem;                 // [4][32*PPITCH] (main loop)
    float*  co = (float*)smem;                  // [4][32*CPITCH] (after loop)
    float*  cl = (float*)(smem + 34816);        // [4][32]

    const int t = threadIdx.x, lane = t & 63, wave = t >> 6;
    const int l16 = lane & 15, quad = lane >> 4;

    const int bid  = blockIdx.x;
    const int head = (bid & 7) >> 1;     // XCD pinning: head per XCD pair
    const int half = bid & 1;            // key half per XCD within pair
    const int p0   = (bid >> 3) * 32;    // qtile 0..127

    const __bf16* Qh = Qb + head * (NPIX * HD);
    const __bf16* Kh = Kb + head * (NPIX * HD);
    const __bf16* Vh = Vb + head * (HD * NPIX);

    bf16x8 bqf[2][2];
    #pragma unroll
    for (int rs = 0; rs < 2; ++rs) {
        const __bf16* qp = Qh + (p0 + rs * 16 + l16) * HD;
        bqf[rs][0] = *(const bf16x8*)(qp + quad * 8);
        bqf[rs][1] = *(const bf16x8*)(qp + 32 + quad * 8);
    }

    f32x4 o_acc[4][2] = {};    // [dt][rs]
    float psv[2] = {0.f, 0.f};
    __bf16* ptw = pt + wave * (32 * PPITCH);
    const int kbase = half * 2048 + wave * 512;

    #pragma unroll 2
    for (int it = 0; it < 8; ++it) {
        const int kb = kbase + it * 64;

        bf16x8 v0[4], v1[4], k0[4], k1[4];
        #pragma unroll
        for (int dt = 0; dt < 4; ++dt) {
            const __bf16* vp = Vh + (dt * 16 + l16) * NPIX + kb;
            v0[dt] = *(const bf16x8*)(vp + quad * 8);
            v1[dt] = *(const bf16x8*)(vp + 32 + quad * 8);
            const __bf16* kp = Kh + (kb + dt * 16 + l16) * HD;
            k0[dt] = *(const bf16x8*)(kp + quad * 8);
            k1[dt] = *(const bf16x8*)(kp + 32 + quad * 8);
        }

        // S^T = K Q^T : C(key = kt*16+quad*4+r, qrow = rs*16+l16)
        f32x4 st[4][2] = {};
        #pragma unroll
        for (int kt = 0; kt < 4; ++kt) {
            #pragma unroll
            for (int rs = 0; rs < 2; ++rs) {
                st[kt][rs] = __builtin_amdgcn_mfma_f32_16x16x32_bf16(k0[kt], bqf[rs][0], st[kt][rs], 0, 0, 0);
                st[kt][rs] = __builtin_amdgcn_mfma_f32_16x16x32_bf16(k1[kt], bqf[rs][1], st[kt][rs], 0, 0, 0);
            }
        }

        // P = exp(S^T); accumulate fp32 psum; packed b64 stores
        #pragma unroll
        for (int kt = 0; kt < 4; ++kt) {
            #pragma unroll
            for (int rs = 0; rs < 2; ++rs) {
                float e0 = __expf(st[kt][rs][0]);
                float e1 = __expf(st[kt][rs][1]);
                float e2 = __expf(st[kt][rs][2]);
                float e3 = __expf(st[kt][rs][3]);
                psv[rs] += (e0 + e1) + (e2 + e3);
                bf16x4 p;
                p[0] = (__bf16)e0; p[1] = (__bf16)e1;
                p[2] = (__bf16)e2; p[3] = (__bf16)e3;
                *(bf16x4*)(ptw + (rs * 16 + l16) * PPITCH + kt * 16 + quad * 4) = p;
            }
        }

        bf16x8 bp[2][2];
        #pragma unroll
        for (int rs = 0; rs < 2; ++rs) {
            bp[rs][0] = *(const bf16x8*)(ptw + (rs * 16 + l16) * PPITCH + quad * 8);
            bp[rs][1] = *(const bf16x8*)(ptw + (rs * 16 + l16) * PPITCH + 32 + quad * 8);
        }

        // O^T += V^T P^T : C(d = dt*16+quad*4+r, qrow = rs*16+l16)
        #pragma unroll
        for (int dt = 0; dt < 4; ++dt) {
            #pragma unroll
            for (int rs = 0; rs < 2; ++rs) {
                o_acc[dt][rs] = __builtin_amdgcn_mfma_f32_16x16x32_bf16(v0[dt], bp[rs][0], o_acc[dt][rs], 0, 0, 0);
                o_acc[dt][rs] = __builtin_amdgcn_mfma_f32_16x16x32_bf16(v1[dt], bp[rs][1], o_acc[dt][rs], 0, 0, 0);
            }
        }
    }

    // l: sum over quads (rows) -> all lanes hold l[qrow = l16] per rs
    #pragma unroll
    for (int rs = 0; rs < 2; ++rs) {
        psv[rs] += __shfl_xor(psv[rs], 16);
        psv[rs] += __shfl_xor(psv[rs], 32);
    }

    __syncthreads();   // all waves done with pt before co overwrites it

    #pragma unroll
    for (int dt = 0; dt < 4; ++dt)
        #pragma unroll
        for (int rs = 0; rs < 2; ++rs)
            *(f32x4*)(co + wave * (32 * CPITCH) + (rs * 16 + l16) * CPITCH + dt * 16 + quad * 4) = o_acc[dt][rs];
    if (quad == 0) {
        cl[wave * 32 + l16]      = psv[0];
        cl[wave * 32 + 16 + l16] = psv[1];
    }
    __syncthreads();

    // merge 4 waves -> fp32 partial to Pb[half], l to Lb[half]
    {
        const int row = t >> 3, dg = (t & 7) * 8;
        f32x4 s0 = {}, s1 = {};
        #pragma unroll
        for (int w = 0; w < 4; ++w) {
            s0 += *(const f32x4*)(co + w * (32 * CPITCH) + row * CPITCH + dg);
            s1 += *(const f32x4*)(co + w * (32 * CPITCH) + row * CPITCH + dg + 4);
        }
        float* Pd = Pb + half * (1 << 20) + (p0 + row) * CCH + head * HD + dg;
        *(f32x4*)(Pd)     = s0;
        *(f32x4*)(Pd + 4) = s1;
        if ((t & 7) == 0) {
            const float l = cl[0 * 32 + row] + cl[1 * 32 + row] + cl[2 * 32 + row] + cl[3 * 32 + row];
            Lb[half * 16384 + head * NPIX + p0 + row] = l;
        }
    }
}

// ---------------------------------------------------------------------------
// K3: proj bf16 MFMA GEMM + half-merge + bias + residual, fp32 out [c][pix].
// Torch scramble: In[c~][p] = flat[c~*4096+p]. Stage (P0+P1)*invl -> bf16
// Bs[p][c~]. grid (128 pixblk32, 2 och). Wave: 16 pix x 64 oc.
// ---------------------------------------------------------------------------
__global__ __launch_bounds__(256) void gemm_proj(
    const float* __restrict__ Pb, const float* __restrict__ Lb,
    const __bf16* __restrict__ Wpb, const float* __restrict__ bias,
    const float* __restrict__ X, float* __restrict__ Out)
{
    __shared__ __bf16 Bs[32 * XPITCH];
    __shared__ float invl[128];

    const int t = threadIdx.x, lane = t & 63, wave = t >> 6;
    const int l16 = lane & 15, quad = lane >> 4;
    const int p0  = blockIdx.x * 32;
    const int och = blockIdx.y;

    if (t < 128) {
        const int hh = t >> 5, p = t & 31;
        invl[t] = 1.f / (Lb[hh * NPIX + p0 + p] + Lb[16384 + hh * NPIX + p0 + p]);
    }
    __syncthreads();

    // stage: thread t owns c~ = t (head = t>>6)
    {
        const int hh = t >> 6;
        const float* P0 = Pb + t * NPIX + p0;
        const float* P1 = P0 + (1 << 20);
        #pragma unroll
        for (int pg = 0; pg < 8; ++pg) {
            f32x4 a = *(const f32x4*)(P0 + pg * 4);
            f32x4 b = *(const f32x4*)(P1 + pg * 4);
            #pragma unroll
            for (int j = 0; j < 4; ++j) {
                const int pl = pg * 4 + j;
                Bs[pl * XPITCH + t] = (__bf16)((a[j] + b[j]) * invl[hh * 32 + pl]);
            }
        }
    }
    __syncthreads();

    const int pixset = wave & 1, ocset = wave >> 1;
    bf16x8 af[8];
    #pragma unroll
    for (int kc = 0; kc < 8; ++kc)
        af[kc] = *(const bf16x8*)(Bs + (pixset * 16 + l16) * XPITCH + kc * 32 + quad * 8);

    #pragma unroll
    for (int u = 0; u < 4; ++u) {
        f32x4 acc = {};
        const int oc_t = och * 128 + ocset * 64 + u * 16;
        #pragma unroll
        for (int kc = 0; kc < 8; ++kc) {
            bf16x8 wf = *(const bf16x8*)(Wpb + (oc_t + l16) * CCH + kc * 32 + quad * 8);
            acc = __builtin_amdgcn_mfma_f32_16x16x32_bf16(af[kc], wf, acc, 0, 0, 0);
        }
        const int oc  = oc_t + l16;
        const int pix = p0 + pixset * 16 + quad * 4;
        const float bz = bias[oc];
        f32x4 r4 = *(const f32x4*)(X + oc * NPIX + pix);
        f32x4 y;
        y[0] = acc[0] + bz + r4[0];
        y[1] = acc[1] + bz + r4[1];
        y[2] = acc[2] + bz + r4[2];
        y[3] = acc[3] + bz + r4[3];
        *(f32x4*)(Out + oc * NPIX + pix) = y;
    }
}

// ---------------------------------------------------------------------------
extern "C" void kernel_launch(void* const* d_in, const int* in_sizes, int n_in,
                              void* d_out, int out_size, void* d_ws, size_t ws_size,
                              hipStream_t stream)
{
    const float* x     = (const float*)d_in[0];
    const float* gamma = (const float*)d_in[1];
    const float* beta  = (const float*)d_in[2];
    const float* Wq    = (const float*)d_in[3];
    const float* bq    = (const float*)d_in[4];
    const float* Wk    = (const float*)d_in[5];
    const float* bk    = (const float*)d_in[6];
    const float* Wv    = (const float*)d_in[7];
    const float* bv    = (const float*)d_in[8];
    const float* Wp    = (const float*)d_in[9];
    const float* bp    = (const float*)d_in[10];
    float* out = (float*)d_out;

    char* ws = (char*)d_ws;
    float*  psum = (float*)(ws);                // 1KB  stats partial sums
    float*  pssq = (float*)(ws + 1024);         // 1KB
    __bf16* Wb   = (__bf16*)(ws + 65536);       // 512KB bf16 4x[256][256]
    __bf16* Qb   = (__bf16*)(ws + (1 << 20));   // 2MB bf16 [head][pix][64]
    __bf16* Kb   = (__bf16*)(ws + (3 << 20));   // 2MB bf16 [head][pix][64]
    __bf16* Vb   = (__bf16*)(ws + (5 << 20));   // 2MB bf16 [c][pix]
    float*  Pb   = (float*)(ws + (7 << 20));    // 8MB fp32 partial O, 2 halves
    float*  Lb   = (float*)(ws + (15 << 20));   // 128KB fp32 partial l, 2 halves

    stats_wconv<<<320, 256, 0, stream>>>(x, Wq, Wk, Wv, Wp, psum, pssq, Wb);

    dim3 gq(64, 6);
    gn_qkv<<<gq, 256, 0, stream>>>(x, gamma, beta, psum, pssq, Wb,
                                   bq, bk, bv, Qb, Kb, Vb);

    attn_mfma<<<1024, 256, 0, stream>>>(Qb, Kb, Vb, Pb, Lb);

    dim3 gp(128, 2);
    gemm_proj<<<gp, 256, 0, stream>>>(Pb, Lb, Wb + 3 * 65536, bp, x, out);
}

// Round 8
// 170.592 us; speedup vs baseline: 1.2462x; 1.2462x over previous
//
#include <hip/hip_runtime.h>
#include <hip/hip_bf16.h>

// b=1, c=256, h=w=64 -> n=4096 pixels, 4 heads, hd=64, 32 groups x 8 ch.
// scale = hd^-0.5 = 0.125, folded into Wq (K0) and bq (K1 epilogue).
#define NPIX 4096
#define CCH  256
#define HD   64
#define GSIZE 32768   // 8 ch * 4096 pix per group

typedef __bf16 bf16x8 __attribute__((ext_vector_type(8)));
typedef __bf16 bf16x4 __attribute__((ext_vector_type(4)));
typedef float  f32x4  __attribute__((ext_vector_type(4)));

#define PPITCH 72    // attn P-tile pitch (bf16)
#define CPITCH 68    // attn combine pitch (f32)
#define XPITCH 264   // X/F panel pitch (bf16)

// MFMA 16x16x32_bf16 layouts (verified m89/m91; used R2-R7):
//   A[m=lane&15][k=quad*8+j]; B[k=quad*8+j][n=lane&15]; C: row=quad*4+reg, col=lane&15

// ---------------------------------------------------------------------------
// K0: blocks 0..255: per-(group,1/8th) partial sums -> psum/pssq[256].
//     blocks 256..319: weight fp32->bf16 convert (Wq scaled 0.125).
// ---------------------------------------------------------------------------
__global__ __launch_bounds__(256) void stats_wconv(
    const float* __restrict__ X,
    const float* __restrict__ Wq, const float* __restrict__ Wk,
    const float* __restrict__ Wv, const float* __restrict__ Wp,
    float* __restrict__ psum, float* __restrict__ pssq, __bf16* __restrict__ Wb)
{
    const int bid = blockIdx.x, t = threadIdx.x;
    if (bid < 256) {
        const float* base = X + bid * 4096;   // (g = bid>>3, seg = bid&7)
        float sum = 0.f, ssq = 0.f;
        #pragma unroll
        for (int k = 0; k < 4; ++k) {
            float4 v = *(const float4*)(base + t * 4 + k * 1024);
            sum += v.x + v.y + v.z + v.w;
            ssq += v.x * v.x + v.y * v.y + v.z * v.z + v.w * v.w;
        }
        #pragma unroll
        for (int off = 1; off < 64; off <<= 1) {
            sum += __shfl_xor(sum, off);
            ssq += __shfl_xor(ssq, off);
        }
        __shared__ float red[2][4];
        const int wv = t >> 6;
        if ((t & 63) == 0) { red[0][wv] = sum; red[1][wv] = ssq; }
        __syncthreads();
        if (t == 0) {
            psum[bid] = red[0][0] + red[0][1] + red[0][2] + red[0][3];
            pssq[bid] = red[1][0] + red[1][1] + red[1][2] + red[1][3];
        }
    } else {
        const int j0 = (bid - 256) * 4096 + t * 16;
        const int m  = j0 >> 16;
        const float* W = (m == 0) ? Wq : (m == 1) ? Wk : (m == 2) ? Wv : Wp;
        const float sc = (m == 0) ? 0.125f : 1.f;
        const int off = j0 & 65535;
        #pragma unroll
        for (int k = 0; k < 4; ++k) {
            float4 v = *(const float4*)(W + off + k * 4);
            bf16x4 o;
            o[0] = (__bf16)(v.x * sc); o[1] = (__bf16)(v.y * sc);
            o[2] = (__bf16)(v.z * sc); o[3] = (__bf16)(v.w * sc);
            *(bf16x4*)(Wb + m * 65536 + off + k * 4) = o;
        }
    }
}

// ---------------------------------------------------------------------------
// K1: fused GroupNorm-apply + QKV MFMA GEMM. grid (64 pixblk, 6: z*2+och).
// Prologue folds the 8 stats partials/group into per-channel affine (LDS).
// Stage affine-applied bf16 X panel [64 pix][256 c]; each wave: 16 pix x 128 oc.
// ---------------------------------------------------------------------------
__global__ __launch_bounds__(256) void gn_qkv(
    const float* __restrict__ X, const float* __restrict__ gamma,
    const float* __restrict__ beta,
    const float* __restrict__ psum, const float* __restrict__ pssq,
    const __bf16* __restrict__ Wb,
    const float* __restrict__ bq, const float* __restrict__ bk,
    const float* __restrict__ bv,
    __bf16* __restrict__ Qb, __bf16* __restrict__ Kb, __bf16* __restrict__ Vb)
{
    __shared__ __bf16 tile[64 * XPITCH];
    __shared__ float al[256], bl[256];

    const int t = threadIdx.x, lane = t & 63, wave = t >> 6;
    const int l16 = lane & 15, quad = lane >> 4;
    const int p0 = blockIdx.x * 64;
    const int z = blockIdx.y >> 1, och = blockIdx.y & 1;

    // per-channel affine coeffs from partials (channel = t)
    {
        const int g = t >> 3;
        float s = 0.f, q = 0.f;
        #pragma unroll
        for (int j = 0; j < 8; ++j) { s += psum[g * 8 + j]; q += pssq[g * 8 + j]; }
        const float mu  = s * (1.f / GSIZE);
        const float var = q * (1.f / GSIZE) - mu * mu;
        const float a = gamma[t] * rsqrtf(var + 1e-6f);
        al[t] = a;
        bl[t] = beta[t] - mu * a;
    }
    __syncthreads();

    // stage: wave w handles channels [w*64, w*64+64), lane = pix
    #pragma unroll 4
    for (int i = 0; i < 16; ++i) {
        const int c4 = wave * 64 + i * 4;
        f32x4 a4 = *(const f32x4*)(al + c4);
        f32x4 b4 = *(const f32x4*)(bl + c4);
        bf16x4 pk;
        pk[0] = (__bf16)(X[(c4 + 0) * NPIX + p0 + lane] * a4[0] + b4[0]);
        pk[1] = (__bf16)(X[(c4 + 1) * NPIX + p0 + lane] * a4[1] + b4[1]);
        pk[2] = (__bf16)(X[(c4 + 2) * NPIX + p0 + lane] * a4[2] + b4[2]);
        pk[3] = (__bf16)(X[(c4 + 3) * NPIX + p0 + lane] * a4[3] + b4[3]);
        *(bf16x4*)(tile + lane * XPITCH + c4) = pk;
    }
    __syncthreads();

    const int pw = wave * 16;
    bf16x8 xf[8];
    #pragma unroll
    for (int kc = 0; kc < 8; ++kc)
        xf[kc] = *(const bf16x8*)(tile + (pw + l16) * XPITCH + kc * 32 + quad * 8);

    const __bf16* Wz = Wb + z * 65536;
    const float* bias = (z == 0) ? bq : (z == 1) ? bk : bv;

    if (z < 2) {
        const float qs = (z == 0) ? 0.125f : 1.f;
        __bf16* dst = (z == 0) ? Qb : Kb;
        #pragma unroll
        for (int grp = 0; grp < 2; ++grp) {
            f32x4 acc[4] = {};
            #pragma unroll
            for (int kc = 0; kc < 8; ++kc) {
                #pragma unroll
                for (int u = 0; u < 4; ++u) {
                    bf16x8 wf = *(const bf16x8*)(Wz + (och * 128 + (grp * 4 + u) * 16 + l16) * CCH + kc * 32 + quad * 8);
                    acc[u] = __builtin_amdgcn_mfma_f32_16x16x32_bf16(wf, xf[kc], acc[u], 0, 0, 0);
                }
            }
            #pragma unroll
            for (int u = 0; u < 4; ++u) {
                const int ot = och * 8 + grp * 4 + u;       // 0..15
                f32x4 bz = *(const f32x4*)(bias + och * 128 + (grp * 4 + u) * 16 + quad * 4);
                bf16x4 o;
                o[0] = (__bf16)(acc[u][0] + bz[0] * qs);
                o[1] = (__bf16)(acc[u][1] + bz[1] * qs);
                o[2] = (__bf16)(acc[u][2] + bz[2] * qs);
                o[3] = (__bf16)(acc[u][3] + bz[3] * qs);
                const int head = ot >> 2, dloc = (ot & 3) * 16 + quad * 4;
                *(bf16x4*)(dst + head * (NPIX * HD) + (p0 + pw + l16) * HD + dloc) = o;
            }
        }
    } else {
        #pragma unroll
        for (int grp = 0; grp < 2; ++grp) {
            f32x4 acc[4] = {};
            #pragma unroll
            for (int kc = 0; kc < 8; ++kc) {
                #pragma unroll
                for (int u = 0; u < 4; ++u) {
                    bf16x8 wf = *(const bf16x8*)(Wz + (och * 128 + (grp * 4 + u) * 16 + l16) * CCH + kc * 32 + quad * 8);
                    acc[u] = __builtin_amdgcn_mfma_f32_16x16x32_bf16(xf[kc], wf, acc[u], 0, 0, 0);
                }
            }
            #pragma unroll
            for (int u = 0; u < 4; ++u) {
                const int oc = och * 128 + (grp * 4 + u) * 16 + l16;
                const float bz = bias[oc];
                bf16x4 o;
                o[0] = (__bf16)(acc[u][0] + bz); o[1] = (__bf16)(acc[u][1] + bz);
                o[2] = (__bf16)(acc[u][2] + bz); o[3] = (__bf16)(acc[u][3] + bz);
                *(bf16x4*)(Vb + oc * NPIX + p0 + pw + quad * 4) = o;
            }
        }
    }
}

// ---------------------------------------------------------------------------
// K2: bf16 MFMA attention, max-free softmax, S^T orientation.
// Block = 1 head x 32 q-rows, 8 WAVES (512 threads); wave w owns keys
// [w*512, (w+1)*512) in 8 iters of 64. No barriers in main loop; no global
// spill (all merging in LDS). l via ones-MFMA (consistent with bf16 P).
// Grid 512 -> 2 blocks/CU co-resident = 16 waves/CU (2x R5 occupancy).
// LDS: per-wave P-tiles unioned with the fp32 merge buffer (lifetimes split
// by barriers). Output bf16 flat F[pix*256 + head*64 + d].
// ---------------------------------------------------------------------------
__global__ __launch_bounds__(512, 4) void attn_mfma(
    const __bf16* __restrict__ Qb, const __bf16* __restrict__ Kb,
    const __bf16* __restrict__ Vb, __bf16* __restrict__ Sb)
{
    // union: [8][32*PPITCH] bf16 P-tiles (36864 B)  |  after barrier:
    //        [4][32*CPITCH] f32 co (34816 B) + [4][32] f32 cl (512 B)
    __shared__ __align__(16) char smem[36864];
    __bf16* pt = (__bf16*)smem;
    float*  co = (float*)smem;
    float*  cl = (float*)(smem + 34816);

    const int t = threadIdx.x, lane = t & 63, wave = t >> 6;
    const int l16 = lane & 15, quad = lane >> 4;

    const int bid  = blockIdx.x;
    const int head = (bid & 7) >> 1;                   // XCD-pair pinning
    const int tile = ((bid >> 3) << 1) | (bid & 1);    // 0..127
    const int p0   = tile * 32;

    const __bf16* Qh = Qb + head * (NPIX * HD);
    const __bf16* Kh = Kb + head * (NPIX * HD);
    const __bf16* Vh = Vb + head * (HD * NPIX);

    // Q B-frags: B[k=d][n=qrow] from layout [qrow][d]
    bf16x8 bqf[2][2];
    #pragma unroll
    for (int rs = 0; rs < 2; ++rs) {
        const __bf16* qp = Qh + (p0 + rs * 16 + l16) * HD;
        bqf[rs][0] = *(const bf16x8*)(qp + quad * 8);
        bqf[rs][1] = *(const bf16x8*)(qp + 32 + quad * 8);
    }

    bf16x8 ones;
    #pragma unroll
    for (int j = 0; j < 8; ++j) ones[j] = (__bf16)1.0f;

    f32x4 l_acc[2] = {};
    f32x4 o_acc[4][2] = {};   // [dt][rs]

    __bf16* ptw = pt + wave * (32 * PPITCH);

    for (int it = 0; it < 8; ++it) {
        const int kb = wave * 512 + it * 64;

        bf16x8 k0[4], k1[4], v0[4], v1[4];
        #pragma unroll
        for (int dt = 0; dt < 4; ++dt) {
            const __bf16* kp = Kh + (kb + dt * 16 + l16) * HD;
            k0[dt] = *(const bf16x8*)(kp + quad * 8);
            k1[dt] = *(const bf16x8*)(kp + 32 + quad * 8);
            const __bf16* vp = Vh + (dt * 16 + l16) * NPIX + kb;
            v0[dt] = *(const bf16x8*)(vp + quad * 8);
            v1[dt] = *(const bf16x8*)(vp + 32 + quad * 8);
        }

        // S^T = K Q^T : C(key = kt*16+quad*4+r, qrow = rs*16+l16)
        f32x4 st[4][2] = {};
        #pragma unroll
        for (int kt = 0; kt < 4; ++kt) {
            #pragma unroll
            for (int rs = 0; rs < 2; ++rs) {
                st[kt][rs] = __builtin_amdgcn_mfma_f32_16x16x32_bf16(k0[kt], bqf[rs][0], st[kt][rs], 0, 0, 0);
                st[kt][rs] = __builtin_amdgcn_mfma_f32_16x16x32_bf16(k1[kt], bqf[rs][1], st[kt][rs], 0, 0, 0);
            }
        }

        // P = exp(S^T), packed b64 stores
        #pragma unroll
        for (int kt = 0; kt < 4; ++kt) {
            #pragma unroll
            for (int rs = 0; rs < 2; ++rs) {
                bf16x4 p;
                p[0] = (__bf16)__expf(st[kt][rs][0]);
                p[1] = (__bf16)__expf(st[kt][rs][1]);
                p[2] = (__bf16)__expf(st[kt][rs][2]);
                p[3] = (__bf16)__expf(st[kt][rs][3]);
                *(bf16x4*)(ptw + (rs * 16 + l16) * PPITCH + kt * 16 + quad * 4) = p;
            }
        }

        // P B-frags (same-wave LDS RAW, waitcnt only)
        bf16x8 bp[2][2];
        #pragma unroll
        for (int rs = 0; rs < 2; ++rs) {
            bp[rs][0] = *(const bf16x8*)(ptw + (rs * 16 + l16) * PPITCH + quad * 8);
            bp[rs][1] = *(const bf16x8*)(ptw + (rs * 16 + l16) * PPITCH + 32 + quad * 8);
        }

        // l += rowsum(P) on the matrix pipe (consistent with bf16 P)
        #pragma unroll
        for (int rs = 0; rs < 2; ++rs) {
            l_acc[rs] = __builtin_amdgcn_mfma_f32_16x16x32_bf16(ones, bp[rs][0], l_acc[rs], 0, 0, 0);
            l_acc[rs] = __builtin_amdgcn_mfma_f32_16x16x32_bf16(ones, bp[rs][1], l_acc[rs], 0, 0, 0);
        }

        // O^T += V^T P^T : C(d = dt*16+quad*4+r, qrow = rs*16+l16)
        #pragma unroll
        for (int dt = 0; dt < 4; ++dt) {
            #pragma unroll
            for (int rs = 0; rs < 2; ++rs) {
                o_acc[dt][rs] = __builtin_amdgcn_mfma_f32_16x16x32_bf16(v0[dt], bp[rs][0], o_acc[dt][rs], 0, 0, 0);
                o_acc[dt][rs] = __builtin_amdgcn_mfma_f32_16x16x32_bf16(v1[dt], bp[rs][1], o_acc[dt][rs], 0, 0, 0);
            }
        }
    }

    // ---- merge: 8 waves -> 4 fp32 partials in LDS -> final sum ----
    __syncthreads();   // all P-tile use done before co overwrites the union

    if (wave >= 4) {   // waves 4..7 write their partials
        float* cw = co + (wave - 4) * (32 * CPITCH);
        #pragma unroll
        for (int dt = 0; dt < 4; ++dt)
            #pragma unroll
            for (int rs = 0; rs < 2; ++rs)
                *(f32x4*)(cw + (rs * 16 + l16) * CPITCH + dt * 16 + quad * 4) = o_acc[dt][rs];
        if (quad == 0) {
            cl[(wave - 4) * 32 + l16]      = l_acc[0][0];
            cl[(wave - 4) * 32 + 16 + l16] = l_acc[1][0];
        }
    }
    __syncthreads();

    if (wave < 4) {    // waves 0..3 add theirs in
        float* cw = co + wave * (32 * CPITCH);
        #pragma unroll
        for (int dt = 0; dt < 4; ++dt)
            #pragma unroll
            for (int rs = 0; rs < 2; ++rs) {
                float* p = cw + (rs * 16 + l16) * CPITCH + dt * 16 + quad * 4;
                *(f32x4*)p = *(const f32x4*)p + o_acc[dt][rs];
            }
        if (quad == 0) {
            cl[wave * 32 + l16]      += l_acc[0][0];
            cl[wave * 32 + 16 + l16] += l_acc[1][0];
        }
    }
    __syncthreads();

    // final: 512 threads x 4 floats = 32 rows x 64 d; divide; bf16 store
    {
        const int row = t >> 4, dg = (t & 15) * 4;
        const float l = cl[row] + cl[32 + row] + cl[64 + row] + cl[96 + row];
        const float inv = 1.f / l;
        f32x4 s = {};
        #pragma unroll
        for (int w = 0; w < 4; ++w)
            s += *(const f32x4*)(co + w * (32 * CPITCH) + row * CPITCH + dg);
        bf16x4 o;
        o[0] = (__bf16)(s[0] * inv); o[1] = (__bf16)(s[1] * inv);
        o[2] = (__bf16)(s[2] * inv); o[3] = (__bf16)(s[3] * inv);
        *(bf16x4*)(Sb + (p0 + row) * CCH + head * HD + dg) = o;
    }
}

// ---------------------------------------------------------------------------
// K3: proj bf16 MFMA GEMM + bias + residual, fp32 out [c][pix].
// Torch scramble: In[c~][p] = F_flat[c~*4096 + p]. Stage panel -> Bs[p][c~].
// grid (128 pixblk32, 2 och). Wave: 16 pix x 64 oc.
// ---------------------------------------------------------------------------
__global__ __launch_bounds__(256) void gemm_proj(
    const __bf16* __restrict__ Sb, const __bf16* __restrict__ Wpb,
    const float* __restrict__ bias, const float* __restrict__ X,
    float* __restrict__ Out)
{
    __shared__ __bf16 Bs[32 * XPITCH];

    const int t = threadIdx.x, lane = t & 63, wave = t >> 6;
    const int l16 = lane & 15, quad = lane >> 4;
    const int p0  = blockIdx.x * 32;
    const int och = blockIdx.y;

    // stage In[c~][p0..p0+31] -> Bs[p][c~]; thread t owns channel c~ = t
    #pragma unroll
    for (int pg = 0; pg < 4; ++pg) {
        bf16x8 v = *(const bf16x8*)(Sb + t * NPIX + p0 + pg * 8);
        #pragma unroll
        for (int j = 0; j < 8; ++j)
            Bs[(pg * 8 + j) * XPITCH + t] = v[j];
    }
    __syncthreads();

    const int pixset = wave & 1, ocset = wave >> 1;
    bf16x8 af[8];
    #pragma unroll
    for (int kc = 0; kc < 8; ++kc)
        af[kc] = *(const bf16x8*)(Bs + (pixset * 16 + l16) * XPITCH + kc * 32 + quad * 8);

    #pragma unroll
    for (int u = 0; u < 4; ++u) {
        f32x4 acc = {};
        const int oc_t = och * 128 + ocset * 64 + u * 16;
        #pragma unroll
        for (int kc = 0; kc < 8; ++kc) {
            bf16x8 wf = *(const bf16x8*)(Wpb + (oc_t + l16) * CCH + kc * 32 + quad * 8);
            acc = __builtin_amdgcn_mfma_f32_16x16x32_bf16(af[kc], wf, acc, 0, 0, 0);
        }
        const int oc  = oc_t + l16;
        const int pix = p0 + pixset * 16 + quad * 4;
        const float bz = bias[oc];
        f32x4 r4 = *(const f32x4*)(X + oc * NPIX + pix);
        f32x4 y;
        y[0] = acc[0] + bz + r4[0];
        y[1] = acc[1] + bz + r4[1];
        y[2] = acc[2] + bz + r4[2];
        y[3] = acc[3] + bz + r4[3];
        *(f32x4*)(Out + oc * NPIX + pix) = y;
    }
}

// ---------------------------------------------------------------------------
extern "C" void kernel_launch(void* const* d_in, const int* in_sizes, int n_in,
                              void* d_out, int out_size, void* d_ws, size_t ws_size,
                              hipStream_t stream)
{
    const float* x     = (const float*)d_in[0];
    const float* gamma = (const float*)d_in[1];
    const float* beta  = (const float*)d_in[2];
    const float* Wq    = (const float*)d_in[3];
    const float* bq    = (const float*)d_in[4];
    const float* Wk    = (const float*)d_in[5];
    const float* bk    = (const float*)d_in[6];
    const float* Wv    = (const float*)d_in[7];
    const float* bv    = (const float*)d_in[8];
    const float* Wp    = (const float*)d_in[9];
    const float* bp    = (const float*)d_in[10];
    float* out = (float*)d_out;

    char* ws = (char*)d_ws;
    float*  psum = (float*)(ws);                // 1KB stats partial sums
    float*  pssq = (float*)(ws + 1024);         // 1KB
    __bf16* Wb   = (__bf16*)(ws + 65536);       // 512KB bf16 4x[256][256]
    __bf16* Qb   = (__bf16*)(ws + (1 << 20));   // 2MB bf16 [head][pix][64]
    __bf16* Kb   = (__bf16*)(ws + (3 << 20));   // 2MB bf16 [head][pix][64]
    __bf16* Vb   = (__bf16*)(ws + (5 << 20));   // 2MB bf16 [c][pix]
    __bf16* Sb   = (__bf16*)(ws + (7 << 20));   // 2MB bf16 flat F

    stats_wconv<<<320, 256, 0, stream>>>(x, Wq, Wk, Wv, Wp, psum, pssq, Wb);

    dim3 gq(64, 6);
    gn_qkv<<<gq, 256, 0, stream>>>(x, gamma, beta, psum, pssq, Wb,
                                   bq, bk, bv, Qb, Kb, Vb);

    attn_mfma<<<512, 512, 0, stream>>>(Qb, Kb, Vb, Sb);

    dim3 gp(128, 2);
    gemm_proj<<<gp, 256, 0, stream>>>(Sb, Wb + 3 * 65536, bp, x, out);
}

// Round 9
// 151.565 us; speedup vs baseline: 1.4026x; 1.1255x over previous
//
#include <hip/hip_runtime.h>
#include <hip/hip_bf16.h>

// b=1, c=256, h=w=64 -> n=4096 pixels, 4 heads, hd=64, 32 groups x 8 ch.
// scale = hd^-0.5 = 0.125, folded into Wq (K0) and bq (K1 epilogue).
#define NPIX 4096
#define CCH  256
#define HD   64
#define GSIZE 32768   // 8 ch * 4096 pix per group

typedef __bf16 bf16x8 __attribute__((ext_vector_type(8)));
typedef __bf16 bf16x4 __attribute__((ext_vector_type(4)));
typedef float  f32x4  __attribute__((ext_vector_type(4)));

#define XPITCH 264   // X/F panel pitch (bf16) for K1/K3

// MFMA 16x16x32_bf16 layouts (verified m89/m91; used R2-R8):
//   A[m=lane&15][k=quad*8+j]; B[k=quad*8+j][n=lane&15]; C: row=quad*4+reg, col=lane&15

// ---------------------------------------------------------------------------
// K0: blocks 0..255: per-(group,1/8th) partial sums -> psum/pssq[256].
//     blocks 256..319: weight fp32->bf16 convert (Wq scaled 0.125).
// ---------------------------------------------------------------------------
__global__ __launch_bounds__(256) void stats_wconv(
    const float* __restrict__ X,
    const float* __restrict__ Wq, const float* __restrict__ Wk,
    const float* __restrict__ Wv, const float* __restrict__ Wp,
    float* __restrict__ psum, float* __restrict__ pssq, __bf16* __restrict__ Wb)
{
    const int bid = blockIdx.x, t = threadIdx.x;
    if (bid < 256) {
        const float* base = X + bid * 4096;   // (g = bid>>3, seg = bid&7)
        float sum = 0.f, ssq = 0.f;
        #pragma unroll
        for (int k = 0; k < 4; ++k) {
            float4 v = *(const float4*)(base + t * 4 + k * 1024);
            sum += v.x + v.y + v.z + v.w;
            ssq += v.x * v.x + v.y * v.y + v.z * v.z + v.w * v.w;
        }
        #pragma unroll
        for (int off = 1; off < 64; off <<= 1) {
            sum += __shfl_xor(sum, off);
            ssq += __shfl_xor(ssq, off);
        }
        __shared__ float red[2][4];
        const int wv = t >> 6;
        if ((t & 63) == 0) { red[0][wv] = sum; red[1][wv] = ssq; }
        __syncthreads();
        if (t == 0) {
            psum[bid] = red[0][0] + red[0][1] + red[0][2] + red[0][3];
            pssq[bid] = red[1][0] + red[1][1] + red[1][2] + red[1][3];
        }
    } else {
        const int j0 = (bid - 256) * 4096 + t * 16;
        const int m  = j0 >> 16;
        const float* W = (m == 0) ? Wq : (m == 1) ? Wk : (m == 2) ? Wv : Wp;
        const float sc = (m == 0) ? 0.125f : 1.f;
        const int off = j0 & 65535;
        #pragma unroll
        for (int k = 0; k < 4; ++k) {
            float4 v = *(const float4*)(W + off + k * 4);
            bf16x4 o;
            o[0] = (__bf16)(v.x * sc); o[1] = (__bf16)(v.y * sc);
            o[2] = (__bf16)(v.z * sc); o[3] = (__bf16)(v.w * sc);
            *(bf16x4*)(Wb + m * 65536 + off + k * 4) = o;
        }
    }
}

// ---------------------------------------------------------------------------
// K1: fused GroupNorm-apply + QKV MFMA GEMM. grid (64 pixblk, 6: z*2+och).
// (unchanged from R8)
// ---------------------------------------------------------------------------
__global__ __launch_bounds__(256) void gn_qkv(
    const float* __restrict__ X, const float* __restrict__ gamma,
    const float* __restrict__ beta,
    const float* __restrict__ psum, const float* __restrict__ pssq,
    const __bf16* __restrict__ Wb,
    const float* __restrict__ bq, const float* __restrict__ bk,
    const float* __restrict__ bv,
    __bf16* __restrict__ Qb, __bf16* __restrict__ Kb, __bf16* __restrict__ Vb)
{
    __shared__ __bf16 tile[64 * XPITCH];
    __shared__ float al[256], bl[256];

    const int t = threadIdx.x, lane = t & 63, wave = t >> 6;
    const int l16 = lane & 15, quad = lane >> 4;
    const int p0 = blockIdx.x * 64;
    const int z = blockIdx.y >> 1, och = blockIdx.y & 1;

    {
        const int g = t >> 3;
        float s = 0.f, q = 0.f;
        #pragma unroll
        for (int j = 0; j < 8; ++j) { s += psum[g * 8 + j]; q += pssq[g * 8 + j]; }
        const float mu  = s * (1.f / GSIZE);
        const float var = q * (1.f / GSIZE) - mu * mu;
        const float a = gamma[t] * rsqrtf(var + 1e-6f);
        al[t] = a;
        bl[t] = beta[t] - mu * a;
    }
    __syncthreads();

    #pragma unroll 4
    for (int i = 0; i < 16; ++i) {
        const int c4 = wave * 64 + i * 4;
        f32x4 a4 = *(const f32x4*)(al + c4);
        f32x4 b4 = *(const f32x4*)(bl + c4);
        bf16x4 pk;
        pk[0] = (__bf16)(X[(c4 + 0) * NPIX + p0 + lane] * a4[0] + b4[0]);
        pk[1] = (__bf16)(X[(c4 + 1) * NPIX + p0 + lane] * a4[1] + b4[1]);
        pk[2] = (__bf16)(X[(c4 + 2) * NPIX + p0 + lane] * a4[2] + b4[2]);
        pk[3] = (__bf16)(X[(c4 + 3) * NPIX + p0 + lane] * a4[3] + b4[3]);
        *(bf16x4*)(tile + lane * XPITCH + c4) = pk;
    }
    __syncthreads();

    const int pw = wave * 16;
    bf16x8 xf[8];
    #pragma unroll
    for (int kc = 0; kc < 8; ++kc)
        xf[kc] = *(const bf16x8*)(tile + (pw + l16) * XPITCH + kc * 32 + quad * 8);

    const __bf16* Wz = Wb + z * 65536;
    const float* bias = (z == 0) ? bq : (z == 1) ? bk : bv;

    if (z < 2) {
        const float qs = (z == 0) ? 0.125f : 1.f;
        __bf16* dst = (z == 0) ? Qb : Kb;
        #pragma unroll
        for (int grp = 0; grp < 2; ++grp) {
            f32x4 acc[4] = {};
            #pragma unroll
            for (int kc = 0; kc < 8; ++kc) {
                #pragma unroll
                for (int u = 0; u < 4; ++u) {
                    bf16x8 wf = *(const bf16x8*)(Wz + (och * 128 + (grp * 4 + u) * 16 + l16) * CCH + kc * 32 + quad * 8);
                    acc[u] = __builtin_amdgcn_mfma_f32_16x16x32_bf16(wf, xf[kc], acc[u], 0, 0, 0);
                }
            }
            #pragma unroll
            for (int u = 0; u < 4; ++u) {
                const int ot = och * 8 + grp * 4 + u;
                f32x4 bz = *(const f32x4*)(bias + och * 128 + (grp * 4 + u) * 16 + quad * 4);
                bf16x4 o;
                o[0] = (__bf16)(acc[u][0] + bz[0] * qs);
                o[1] = (__bf16)(acc[u][1] + bz[1] * qs);
                o[2] = (__bf16)(acc[u][2] + bz[2] * qs);
                o[3] = (__bf16)(acc[u][3] + bz[3] * qs);
                const int head = ot >> 2, dloc = (ot & 3) * 16 + quad * 4;
                *(bf16x4*)(dst + head * (NPIX * HD) + (p0 + pw + l16) * HD + dloc) = o;
            }
        }
    } else {
        #pragma unroll
        for (int grp = 0; grp < 2; ++grp) {
            f32x4 acc[4] = {};
            #pragma unroll
            for (int kc = 0; kc < 8; ++kc) {
                #pragma unroll
                for (int u = 0; u < 4; ++u) {
                    bf16x8 wf = *(const bf16x8*)(Wz + (och * 128 + (grp * 4 + u) * 16 + l16) * CCH + kc * 32 + quad * 8);
                    acc[u] = __builtin_amdgcn_mfma_f32_16x16x32_bf16(xf[kc], wf, acc[u], 0, 0, 0);
                }
            }
            #pragma unroll
            for (int u = 0; u < 4; ++u) {
                const int oc = och * 128 + (grp * 4 + u) * 16 + l16;
                const float bz = bias[oc];
                bf16x4 o;
                o[0] = (__bf16)(acc[u][0] + bz); o[1] = (__bf16)(acc[u][1] + bz);
                o[2] = (__bf16)(acc[u][2] + bz); o[3] = (__bf16)(acc[u][3] + bz);
                *(bf16x4*)(Vb + oc * NPIX + p0 + pw + quad * 4) = o;
            }
        }
    }
}

// ---------------------------------------------------------------------------
// K2: bf16 MFMA attention, L2-line-efficient LDS-staged version.
// Grid 256: (head 4) x (q-tile of 64 rows). Block = 4 waves (256 thr).
// Waves SHARE the 64 q-rows and SPLIT each 128-key tile 4 ways (32 keys/wave;
// key order within softmax is permutation-invariant).
// K/V staged per tile into LDS with FULL-128B-LINE coalesced loads (each L2
// line read once per block, fully consumed), register-prefetch double-buffer,
// 1 barrier/tile. Max-free softmax; l via ones-MFMA; in-LDS 4-way key merge.
// Output bf16 flat F[pix*256 + head*64 + d].
// ---------------------------------------------------------------------------
#define KPITCH 72    // kt [key128][d64] pitch (bf16), 144 B rows
#define VPITCH 136   // vt [d64][key128] pitch (bf16), 272 B rows
#define PPIT   40    // pt per-wave [row64][key32] pitch (bf16), 80 B rows
#define KBUF   (128 * KPITCH)           // 9216 elems
#define VBUF   (64 * VPITCH)            // 8704 elems
#define OFF_K  0
#define OFF_V  (2 * KBUF * 2)           // 36864 B
#define OFF_P  (OFF_V + 2 * VBUF * 2)   // 71680 B
#define SMEMSZ (OFF_P + 4 * 64 * PPIT * 2)  // 92160 B

__global__ __launch_bounds__(256, 1) void attn_mfma(
    const __bf16* __restrict__ Qb, const __bf16* __restrict__ Kb,
    const __bf16* __restrict__ Vb, __bf16* __restrict__ Sb)
{
    __shared__ __align__(16) char smem[SMEMSZ];
    __bf16* ktls = (__bf16*)(smem + OFF_K);
    __bf16* vtls = (__bf16*)(smem + OFF_V);
    __bf16* ptls = (__bf16*)(smem + OFF_P);
    float*  co   = (float*)smem;                 // merge overlay (after loop)
    float*  cl   = (float*)(smem + 69632);

    const int t = threadIdx.x, lane = t & 63, wave = t >> 6;
    const int l16 = lane & 15, quad = lane >> 4;

    const int bid  = blockIdx.x;
    const int head = (bid & 7) >> 1;                   // XCD-pair pinning
    const int qt   = ((bid >> 3) << 1) | (bid & 1);    // 0..63
    const int p0   = qt * 64;

    const __bf16* Qh = Qb + head * (NPIX * HD);
    const __bf16* Kh = Kb + head * (NPIX * HD);
    const __bf16* Vh = Vb + head * (HD * NPIX);

    // Q B-frags for 64 shared rows: B[k=d][n=row16], rt = row-tile
    bf16x8 qf[4][2];
    #pragma unroll
    for (int rt = 0; rt < 4; ++rt) {
        const __bf16* qp = Qh + (p0 + rt * 16 + l16) * HD + quad * 8;
        qf[rt][0] = *(const bf16x8*)(qp);
        qf[rt][1] = *(const bf16x8*)(qp + 32);
    }

    bf16x8 ones;
    #pragma unroll
    for (int j = 0; j < 8; ++j) ones[j] = (__bf16)1.0f;

    f32x4 l_acc[4] = {};
    f32x4 o_acc[4][4] = {};   // [dt][rt]

    __bf16* ptw = ptls + wave * (64 * PPIT);

    // prefetch regs: 4 x 16B chunks each for K and V (full-line coalesced)
    bf16x8 kpre[4], vpre[4];
    #pragma unroll
    for (int i = 0; i < 4; ++i) {
        const int c = t + 256 * i;
        kpre[i] = *(const bf16x8*)(Kh + (c >> 3) * HD + (c & 7) * 8);
        vpre[i] = *(const bf16x8*)(Vh + (c >> 4) * NPIX + (c & 15) * 8);
    }

    for (int it = 0; it < 32; ++it) {
        const int b = it & 1;
        __bf16* ktb = ktls + b * KBUF;
        __bf16* vtb = vtls + b * VBUF;

        // write prefetched tile -> LDS buf b
        #pragma unroll
        for (int i = 0; i < 4; ++i) {
            const int c = t + 256 * i;
            *(bf16x8*)(ktb + (c >> 3) * KPITCH + (c & 7) * 8)  = kpre[i];
            *(bf16x8*)(vtb + (c >> 4) * VPITCH + (c & 15) * 8) = vpre[i];
        }
        __syncthreads();

        // issue next tile's global loads (consumed next iter)
        if (it < 31) {
            const int kb = (it + 1) * 128;
            #pragma unroll
            for (int i = 0; i < 4; ++i) {
                const int c = t + 256 * i;
                kpre[i] = *(const bf16x8*)(Kh + (kb + (c >> 3)) * HD + (c & 7) * 8);
                vpre[i] = *(const bf16x8*)(Vh + (c >> 4) * NPIX + kb + (c & 15) * 8);
            }
        }

        // ---- compute tile it from buf b; wave owns local keys [wave*32,+32) ----
        bf16x8 kf[2][2], vf[4];
        #pragma unroll
        for (int kt = 0; kt < 2; ++kt) {
            const __bf16* kp = ktb + (wave * 32 + kt * 16 + l16) * KPITCH + quad * 8;
            kf[kt][0] = *(const bf16x8*)(kp);
            kf[kt][1] = *(const bf16x8*)(kp + 32);
        }
        #pragma unroll
        for (int dt = 0; dt < 4; ++dt)
            vf[dt] = *(const bf16x8*)(vtb + (dt * 16 + l16) * VPITCH + wave * 32 + quad * 8);

        // S^T = K Q^T : C(key_local = kt*16+quad*4+r, row = rt*16+l16)
        f32x4 st[2][4] = {};
        #pragma unroll
        for (int kt = 0; kt < 2; ++kt)
            #pragma unroll
            for (int rt = 0; rt < 4; ++rt) {
                st[kt][rt] = __builtin_amdgcn_mfma_f32_16x16x32_bf16(kf[kt][0], qf[rt][0], st[kt][rt], 0, 0, 0);
                st[kt][rt] = __builtin_amdgcn_mfma_f32_16x16x32_bf16(kf[kt][1], qf[rt][1], st[kt][rt], 0, 0, 0);
            }

        // P = exp(S^T) -> per-wave P tile [row][key_local 32]
        #pragma unroll
        for (int kt = 0; kt < 2; ++kt)
            #pragma unroll
            for (int rt = 0; rt < 4; ++rt) {
                bf16x4 p;
                p[0] = (__bf16)__expf(st[kt][rt][0]);
                p[1] = (__bf16)__expf(st[kt][rt][1]);
                p[2] = (__bf16)__expf(st[kt][rt][2]);
                p[3] = (__bf16)__expf(st[kt][rt][3]);
                *(bf16x4*)(ptw + (rt * 16 + l16) * PPIT + kt * 16 + quad * 4) = p;
            }

        // P B-frags (same-wave LDS RAW): B[k=key_local][n=row]
        bf16x8 bp[4];
        #pragma unroll
        for (int rt = 0; rt < 4; ++rt)
            bp[rt] = *(const bf16x8*)(ptw + (rt * 16 + l16) * PPIT + quad * 8);

        // l += rowsum(P) on the matrix pipe
        #pragma unroll
        for (int rt = 0; rt < 4; ++rt)
            l_acc[rt] = __builtin_amdgcn_mfma_f32_16x16x32_bf16(ones, bp[rt], l_acc[rt], 0, 0, 0);

        // O^T += V^T P^T : C(d = dt*16+quad*4+r, row = rt*16+l16)
        #pragma unroll
        for (int dt = 0; dt < 4; ++dt)
            #pragma unroll
            for (int rt = 0; rt < 4; ++rt)
                o_acc[dt][rt] = __builtin_amdgcn_mfma_f32_16x16x32_bf16(vf[dt], bp[rt], o_acc[dt][rt], 0, 0, 0);
        // no trailing barrier: next iter writes buf b^1 while stragglers read b
    }

    // ---- in-LDS 4-way key merge ----
    __syncthreads();   // everyone done with K/V/P LDS before overlay

    #pragma unroll
    for (int dt = 0; dt < 4; ++dt)
        #pragma unroll
        for (int rt = 0; rt < 4; ++rt)
            *(f32x4*)(co + wave * 4352 + (rt * 16 + l16) * 68 + dt * 16 + quad * 4) = o_acc[dt][rt];
    if (quad == 0) {
        #pragma unroll
        for (int rt = 0; rt < 4; ++rt)
            cl[wave * 64 + rt * 16 + l16] = l_acc[rt][0];
    }
    __syncthreads();

    {
        const int row = t >> 2, dc = (t & 3) * 16;
        const float l = cl[row] + cl[64 + row] + cl[128 + row] + cl[192 + row];
        const float inv = 1.f / l;
        f32x4 s[4];
        #pragma unroll
        for (int j = 0; j < 4; ++j) {
            s[j] = f32x4{0.f, 0.f, 0.f, 0.f};
            #pragma unroll
            for (int w = 0; w < 4; ++w)
                s[j] += *(const f32x4*)(co + w * 4352 + row * 68 + dc + j * 4);
        }
        bf16x8 o1, o2;
        #pragma unroll
        for (int j = 0; j < 4; ++j) {
            o1[j]     = (__bf16)(s[0][j] * inv);
            o1[j + 4] = (__bf16)(s[1][j] * inv);
            o2[j]     = (__bf16)(s[2][j] * inv);
            o2[j + 4] = (__bf16)(s[3][j] * inv);
        }
        __bf16* dst = Sb + (p0 + row) * CCH + head * HD + dc;
        *(bf16x8*)(dst)     = o1;
        *(bf16x8*)(dst + 8) = o2;
    }
}

// ---------------------------------------------------------------------------
// K3: proj bf16 MFMA GEMM + bias + residual, fp32 out [c][pix].
// (unchanged from R8)
// ---------------------------------------------------------------------------
__global__ __launch_bounds__(256) void gemm_proj(
    const __bf16* __restrict__ Sb, const __bf16* __restrict__ Wpb,
    const float* __restrict__ bias, const float* __restrict__ X,
    float* __restrict__ Out)
{
    __shared__ __bf16 Bs[32 * XPITCH];

    const int t = threadIdx.x, lane = t & 63, wave = t >> 6;
    const int l16 = lane & 15, quad = lane >> 4;
    const int p0  = blockIdx.x * 32;
    const int och = blockIdx.y;

    #pragma unroll
    for (int pg = 0; pg < 4; ++pg) {
        bf16x8 v = *(const bf16x8*)(Sb + t * NPIX + p0 + pg * 8);
        #pragma unroll
        for (int j = 0; j < 8; ++j)
            Bs[(pg * 8 + j) * XPITCH + t] = v[j];
    }
    __syncthreads();

    const int pixset = wave & 1, ocset = wave >> 1;
    bf16x8 af[8];
    #pragma unroll
    for (int kc = 0; kc < 8; ++kc)
        af[kc] = *(const bf16x8*)(Bs + (pixset * 16 + l16) * XPITCH + kc * 32 + quad * 8);

    #pragma unroll
    for (int u = 0; u < 4; ++u) {
        f32x4 acc = {};
        const int oc_t = och * 128 + ocset * 64 + u * 16;
        #pragma unroll
        for (int kc = 0; kc < 8; ++kc) {
            bf16x8 wf = *(const bf16x8*)(Wpb + (oc_t + l16) * CCH + kc * 32 + quad * 8);
            acc = __builtin_amdgcn_mfma_f32_16x16x32_bf16(af[kc], wf, acc, 0, 0, 0);
        }
        const int oc  = oc_t + l16;
        const int pix = p0 + pixset * 16 + quad * 4;
        const float bz = bias[oc];
        f32x4 r4 = *(const f32x4*)(X + oc * NPIX + pix);
        f32x4 y;
        y[0] = acc[0] + bz + r4[0];
        y[1] = acc[1] + bz + r4[1];
        y[2] = acc[2] + bz + r4[2];
        y[3] = acc[3] + bz + r4[3];
        *(f32x4*)(Out + oc * NPIX + pix) = y;
    }
}

// ---------------------------------------------------------------------------
extern "C" void kernel_launch(void* const* d_in, const int* in_sizes, int n_in,
                              void* d_out, int out_size, void* d_ws, size_t ws_size,
                              hipStream_t stream)
{
    const float* x     = (const float*)d_in[0];
    const float* gamma = (const float*)d_in[1];
    const float* beta  = (const float*)d_in[2];
    const float* Wq    = (const float*)d_in[3];
    const float* bq    = (const float*)d_in[4];
    const float* Wk    = (const float*)d_in[5];
    const float* bk    = (const float*)d_in[6];
    const float* Wv    = (const float*)d_in[7];
    const float* bv    = (const float*)d_in[8];
    const float* Wp    = (const float*)d_in[9];
    const float* bp    = (const float*)d_in[10];
    float* out = (float*)d_out;

    char* ws = (char*)d_ws;
    float*  psum = (float*)(ws);                // 1KB stats partial sums
    float*  pssq = (float*)(ws + 1024);         // 1KB
    __bf16* Wb   = (__bf16*)(ws + 65536);       // 512KB bf16 4x[256][256]
    __bf16* Qb   = (__bf16*)(ws + (1 << 20));   // 2MB bf16 [head][pix][64]
    __bf16* Kb   = (__bf16*)(ws + (3 << 20));   // 2MB bf16 [head][pix][64]
    __bf16* Vb   = (__bf16*)(ws + (5 << 20));   // 2MB bf16 [c][pix]
    __bf16* Sb   = (__bf16*)(ws + (7 << 20));   // 2MB bf16 flat F

    stats_wconv<<<320, 256, 0, stream>>>(x, Wq, Wk, Wv, Wp, psum, pssq, Wb);

    dim3 gq(64, 6);
    gn_qkv<<<gq, 256, 0, stream>>>(x, gamma, beta, psum, pssq, Wb,
                                   bq, bk, bv, Qb, Kb, Vb);

    attn_mfma<<<256, 256, 0, stream>>>(Qb, Kb, Vb, Sb);

    dim3 gp(128, 2);
    gemm_proj<<<gp, 256, 0, stream>>>(Sb, Wb + 3 * 65536, bp, x, out);
}